// Round 7
// baseline (1553.489 us; speedup 1.0000x reference)
//
#include <hip/hip_runtime.h>
#include <math.h>

#define KK 20
#define NPTS 1024
#define BB 8
#define EPSF 1e-5f

// ====================== KNN: wave-per-point =============================
// xxs computed in-block, fp64 fma ascending c -> bitwise equal to the dot
// chain, so self distance is exactly 0. Selection: 20 rounds of local
// argmax + 64-lane butterfly, lowest-index tie-break, no __syncthreads.
__device__ __forceinline__ void select20(double (&d)[16], int lane, int* orow)
{
  int keep = 0;
  for (int s = 0; s < KK; ++s) {
    double bd = d[0]; int bj = 0;
    #pragma unroll
    for (int j = 1; j < 16; ++j)
      if (d[j] > bd) { bd = d[j]; bj = j; }     // strict > keeps lowest j (lowest m)
    int bi = bj * 64 + lane;
    #pragma unroll
    for (int o = 1; o < 64; o <<= 1) {
      double od = __shfl_xor(bd, o, 64);
      int    oi = __shfl_xor(bi, o, 64);
      if (od > bd || (od == bd && oi < bi)) { bd = od; bi = oi; }
    }
    if (lane == s) keep = bi;
    if ((bi & 63) == lane) {
      int jw = bi >> 6;
      #pragma unroll
      for (int j = 0; j < 16; ++j)
        if (j == jw) d[j] = -INFINITY;
    }
  }
  if (lane < KK) orow[lane] = keep;
}

template <int C, int CH>
__global__ __launch_bounds__(256) void knn2_kernel(
    const float* __restrict__ x, long bstride,
    int* __restrict__ idx_out)
{
  const int t = threadIdx.x, w = t >> 6, lane = t & 63;
  const int b = blockIdx.y;
  const int n0 = blockIdx.x * 8;
  const int pa = n0 + 2 * w, pb = pa + 1;
  __shared__ float  xs[CH][NPTS];
  __shared__ double xxs[NPTS];
  const float* xb = x + (long)b * bstride;

  for (int i = t; i < NPTS; i += 256) xxs[i] = 0.0;

  double dotA[16], dotB[16];
  #pragma unroll
  for (int j = 0; j < 16; ++j) { dotA[j] = 0.0; dotB[j] = 0.0; }

  for (int c0 = 0; c0 < C; c0 += CH) {
    __syncthreads();
    for (int i = t; i < CH * NPTS; i += 256)
      (&xs[0][0])[i] = xb[(long)(c0 + (i >> 10)) * NPTS + (i & (NPTS - 1))];
    __syncthreads();
    for (int m = t; m < NPTS; m += 256) {
      double s = xxs[m];
      #pragma unroll
      for (int cc = 0; cc < CH; ++cc) {
        double v = (double)xs[cc][m];
        s = fma(v, v, s);
      }
      xxs[m] = s;
    }
    #pragma unroll
    for (int cc = 0; cc < CH; ++cc) {
      double ca = (double)xs[cc][pa];
      double cb = (double)xs[cc][pb];
      #pragma unroll
      for (int j = 0; j < 16; ++j) {
        double v = (double)xs[cc][j * 64 + lane];
        dotA[j] = fma(ca, v, dotA[j]);
        dotB[j] = fma(cb, v, dotB[j]);
      }
    }
  }
  __syncthreads();

  double xxA = xxs[pa], xxB = xxs[pb];
  double dA[16], dB[16];
  #pragma unroll
  for (int j = 0; j < 16; ++j) {
    double xm = xxs[j * 64 + lane];
    dA[j] = (2.0 * dotA[j] - xxA) - xm;
    dB[j] = (2.0 * dotB[j] - xxB) - xm;
  }
  select20(dA, lane, idx_out + ((long)b * NPTS + pa) * KK);
  select20(dB, lane, idx_out + ((long)b * NPTS + pb) * KK);
}

// =============== center-term GEMV: Yc[b][n][o] = sum_c wd*x ============
// wd = (W2-W1) computed in fp32 (same as old ec), AccT accumulate, c asc
// -> bit-identical to the old in-ec cacc chain.
template <typename AccT, int C, int O, int CB2, int TN>
__global__ __launch_bounds__(256) void cacc_kernel(
    const float* __restrict__ x, long bstride,
    const float* __restrict__ W,
    AccT* __restrict__ Yc)
{
  const int t = threadIdx.x, b = blockIdx.y;
  const int o = t & (O - 1);
  const int nbase = (t / O) * 16;
  const int nn0 = blockIdx.x * TN;
  __shared__ float s_wd[CB2 * O];
  __shared__ float s_xs[CB2 * TN];
  const float* xb = x + (long)b * bstride;

  AccT acc[16];
  #pragma unroll
  for (int j = 0; j < 16; ++j) acc[j] = (AccT)0;

  for (int c0 = 0; c0 < C; c0 += CB2) {
    __syncthreads();
    for (int i = t; i < CB2 * O; i += 256) {
      int oo = i / CB2, cc = i - oo * CB2;
      float a  = W[(long)oo * (2 * C) + c0 + cc];
      float b2 = W[(long)oo * (2 * C) + C + c0 + cc];
      s_wd[cc * O + oo] = b2 - a;
    }
    for (int i = t; i < CB2 * TN; i += 256) {
      int cc = i / TN, nn = i - cc * TN;
      s_xs[cc * TN + nn] = xb[(long)(c0 + cc) * NPTS + nn0 + nn];
    }
    __syncthreads();
    #pragma unroll
    for (int cc = 0; cc < CB2; ++cc) {
      float wv = s_wd[cc * O + o];
      #pragma unroll
      for (int j = 0; j < 16; ++j)
        acc[j] += (AccT)wv * (AccT)s_xs[cc * TN + nbase + j];
    }
  }
  #pragma unroll
  for (int j = 0; j < 16; ++j) {
    int n = nn0 + nbase + j;
    Yc[((long)b * NPTS + n) * O + o] = acc[j];
  }
}

// ==================== Fused EdgeConv (single pass) ======================
// y[o][n][k] = sum_c w1[o][c]*x[c][j_k] + Yc[o][n]   (center term hoisted)
// Raw max over k (norm+lrelu monotone, gamma>0) + sum/sumsq for BN stats.
// Block: 512 thr = 8 waves = 8 points; lane owns RO channels. w1-only LDS,
// xg k-contiguous -> per cc: 1 strided b128 + 5 broadcast b128 vs 80 FMA.
template <typename AccT, int C, int O, int RO, int CB>
__global__ __launch_bounds__(512) void ec_fused(
    const float* __restrict__ x, long bstride,
    const int* __restrict__ idx,
    const float* __restrict__ W,
    const AccT* __restrict__ Yc,
    double* __restrict__ sums,
    AccT* __restrict__ yraw)          // [b][n][O] raw max over k
{
  const int t = threadIdx.x, b = blockIdx.y;
  const int p = t >> 6, lane = t & 63;
  const int n0 = blockIdx.x * 8;
  const int n = n0 + p;
  const int obase = lane * RO;
  const int OP = O + 4;
  const float* xb = x + (long)b * bstride;

  extern __shared__ char smraw[];
  float* s_w1 = (float*)smraw;               // [CB][OP]
  float* s_xg = s_w1 + CB * OP;              // [8][CB][24] gathered nbr x
  int*   s_jj = (int*)(s_xg + 8 * CB * 24);  // [8][KK]
  AccT*  red  = (AccT*)smraw;                // epilogue alias: [2][8][O]

  if (t < 8 * KK) {
    int pp = t / KK, k = t - pp * KK;
    s_jj[t] = idx[((long)b * NPTS + (n0 + pp)) * KK + k];
  }

  AccT kacc[RO][KK];
  #pragma unroll
  for (int r = 0; r < RO; ++r)
    #pragma unroll
    for (int k = 0; k < KK; ++k) kacc[r][k] = (AccT)0;

  for (int c0 = 0; c0 < C; c0 += CB) {
    __syncthreads();
    for (int i = t; i < CB * O; i += 512) {
      int o = i / CB, cc = i - o * CB;
      s_w1[cc * OP + o] = W[(long)o * (2 * C) + c0 + cc];
    }
    for (int i = t; i < 8 * CB * KK; i += 512) {
      int k = i % KK; int pc = i / KK;
      int cc = pc % CB; int pp = pc / CB;
      s_xg[(pp * CB + cc) * 24 + k] = xb[(long)(c0 + cc) * NPTS + s_jj[pp * KK + k]];
    }
    __syncthreads();
    for (int cc = 0; cc < CB; ++cc) {
      float wv[RO];
      if constexpr (RO == 4) {
        float4 a = *(const float4*)&s_w1[cc * OP + obase];
        wv[0]=a.x; wv[1]=a.y; wv[2]=a.z; wv[3]=a.w;
      } else if constexpr (RO == 2) {
        float2 a = *(const float2*)&s_w1[cc * OP + obase];
        wv[0]=a.x; wv[1]=a.y;
      } else {
        wv[0] = s_w1[cc * OP + obase];
      }
      const float* fp = s_xg + (p * CB + cc) * 24;
      #pragma unroll
      for (int k4 = 0; k4 < KK; k4 += 4) {
        float4 f4 = *(const float4*)(fp + k4);   // wave-uniform broadcast b128
        float fe[4] = {f4.x, f4.y, f4.z, f4.w};
        #pragma unroll
        for (int e = 0; e < 4; ++e) {
          #pragma unroll
          for (int r = 0; r < RO; ++r)
            kacc[r][k4 + e] += (AccT)wv[r] * (AccT)fe[e];
        }
      }
    }
  }

  // center term (precomputed), then per-thread max/sum/sumsq over k
  AccT cacc[RO];
  const AccT* ycp = Yc + ((long)b * NPTS + n) * O + obase;
  #pragma unroll
  for (int r = 0; r < RO; ++r) cacc[r] = ycp[r];

  AccT psum[RO], psq[RO], pmx[RO];
  #pragma unroll
  for (int r = 0; r < RO; ++r) { psum[r] = (AccT)0; psq[r] = (AccT)0; pmx[r] = (AccT)(-INFINITY); }
  #pragma unroll
  for (int k = 0; k < KK; ++k) {
    #pragma unroll
    for (int r = 0; r < RO; ++r) {
      AccT y = kacc[r][k] + cacc[r];
      psum[r] += y; psq[r] += y * y;
      pmx[r] = (y > pmx[r]) ? y : pmx[r];
    }
  }
  #pragma unroll
  for (int r = 0; r < RO; ++r)
    yraw[((long)b * NPTS + n) * O + obase + r] = pmx[r];

  __syncthreads();
  #pragma unroll
  for (int r = 0; r < RO; ++r) {
    red[p * O + obase + r] = psum[r];
    red[8 * O + p * O + obase + r] = psq[r];
  }
  __syncthreads();
  if (t < O) {
    double s = 0.0, q = 0.0;
    #pragma unroll
    for (int w = 0; w < 8; ++w) {
      s += (double)red[w * O + t];
      q += (double)red[8 * O + w * O + t];
    }
    atomicAdd(&sums[t], s);
    atomicAdd(&sums[1024 + t], q);
  }
}

// normalize + lrelu the raw k-max, write into cat layout [b][o][n]
template <typename AccT, int O, int OL>
__global__ __launch_bounds__(256) void ec_norm(
    const AccT* __restrict__ yraw, const double* __restrict__ sums,
    const float* __restrict__ gamma, const float* __restrict__ beta,
    float* __restrict__ xout)
{
  int i = blockIdx.x * 256 + threadIdx.x;
  int n = i & (NPTS - 1);
  int o = (i >> 10) & (O - 1);
  int b = i >> (10 + OL);
  const double cnt = (double)BB * NPTS * KK;
  double m = sums[o] / cnt;
  double var = sums[1024 + o] / cnt - m * m;
  double inv = 1.0 / sqrt(var + (double)EPSF);
  AccT y = yraw[((long)b * NPTS + n) * O + o];
  AccT v = (y - (AccT)m) * (AccT)inv * (AccT)gamma[o] + (AccT)beta[o];
  v = (v >= (AccT)0) ? v : (AccT)0.2 * v;
  xout[(long)b * (512L * NPTS) + (long)o * NPTS + n] = (float)v;
}

// ============== Final 512->1024 conv, fused single pass =================
__device__ inline unsigned fkey(float f) {
  unsigned u = __float_as_uint(f);
  return (u & 0x80000000u) ? ~u : (u | 0x80000000u);
}
__device__ inline float keyf(unsigned k) {
  return __uint_as_float((k & 0x80000000u) ? (k ^ 0x80000000u) : ~k);
}

#define WST 524

__global__ __launch_bounds__(256) void fin_fused(
    const float* __restrict__ cat, const float* __restrict__ W5,
    double* __restrict__ sums, unsigned* __restrict__ mkeys)
{
  const int nt = blockIdx.x, ot = blockIdx.y, t = threadIdx.x;
  const int w = t >> 6, lane = t & 63;
  const int col0 = nt * 32;
  const int b = col0 >> 10;
  const int nb = col0 & 1023;

  __shared__ float sm[16 * WST + 16 * 32];
  float* s_w = sm;
  float* s_f = sm + 16 * WST;

  float acc[2][4][8];
  #pragma unroll
  for (int h = 0; h < 2; ++h)
    #pragma unroll
    for (int r = 0; r < 4; ++r)
      #pragma unroll
      for (int j = 0; j < 8; ++j) acc[h][r][j] = 0.f;

  for (int c0 = 0; c0 < 512; c0 += 16) {
    __syncthreads();
    for (int i = t; i < 16 * 512 / 4; i += 256) {
      int o = i >> 2, cq = (i & 3) * 4;
      float4 wv = *(const float4*)&W5[(long)(ot * 512 + o) * 512 + c0 + cq];
      s_w[(cq + 0) * WST + o] = wv.x;
      s_w[(cq + 1) * WST + o] = wv.y;
      s_w[(cq + 2) * WST + o] = wv.z;
      s_w[(cq + 3) * WST + o] = wv.w;
    }
    for (int i = t; i < 16 * 32; i += 256) {
      int cc = i >> 5, nn = i & 31;
      s_f[cc * 32 + nn] = cat[((long)b * 512 + c0 + cc) * 1024 + nb + nn];
    }
    __syncthreads();
    #pragma unroll
    for (int cc = 0; cc < 16; ++cc) {
      float4 wA = *(const float4*)&s_w[cc * WST + lane * 4];
      float4 wB = *(const float4*)&s_w[cc * WST + 256 + lane * 4];
      float4 f0 = *(const float4*)&s_f[cc * 32 + w * 8];
      float4 f1 = *(const float4*)&s_f[cc * 32 + w * 8 + 4];
      float wa[4] = {wA.x, wA.y, wA.z, wA.w};
      float wb[4] = {wB.x, wB.y, wB.z, wB.w};
      float fv[8] = {f0.x, f0.y, f0.z, f0.w, f1.x, f1.y, f1.z, f1.w};
      #pragma unroll
      for (int r = 0; r < 4; ++r)
        #pragma unroll
        for (int j = 0; j < 8; ++j) {
          acc[0][r][j] += wa[r] * fv[j];
          acc[1][r][j] += wb[r] * fv[j];
        }
    }
  }

  float psum[2][4], psq[2][4], pmx[2][4];
  #pragma unroll
  for (int h = 0; h < 2; ++h)
    #pragma unroll
    for (int r = 0; r < 4; ++r) {
      psum[h][r] = 0.f; psq[h][r] = 0.f; pmx[h][r] = -INFINITY;
      #pragma unroll
      for (int j = 0; j < 8; ++j) {
        float v = acc[h][r][j];
        psum[h][r] += v; psq[h][r] += v * v; pmx[h][r] = fmaxf(pmx[h][r], v);
      }
    }
  __syncthreads();
  float* red_s = sm;
  float* red_q = sm + 2048;
  float* red_m = sm + 4096;
  #pragma unroll
  for (int h = 0; h < 2; ++h)
    #pragma unroll
    for (int r = 0; r < 4; ++r) {
      int oo = h * 256 + lane * 4 + r;
      red_s[w * 512 + oo] = psum[h][r];
      red_q[w * 512 + oo] = psq[h][r];
      red_m[w * 512 + oo] = pmx[h][r];
    }
  __syncthreads();
  for (int oo = t; oo < 512; oo += 256) {
    float s = 0.f, q = 0.f, m = -INFINITY;
    #pragma unroll
    for (int ww = 0; ww < 4; ++ww) {
      s += red_s[ww * 512 + oo];
      q += red_q[ww * 512 + oo];
      m = fmaxf(m, red_m[ww * 512 + oo]);
    }
    int o = ot * 512 + oo;
    atomicAdd(&sums[o], (double)s);
    atomicAdd(&sums[1024 + o], (double)q);
    atomicMax(&mkeys[b * 1024 + o], fkey(m));
  }
}

__global__ __launch_bounds__(256) void fin_norm(
    const unsigned* __restrict__ mkeys, const double* __restrict__ sums,
    const float* __restrict__ g, const float* __restrict__ bt,
    float* __restrict__ out)
{
  int i = blockIdx.x * 256 + threadIdx.x;   // 8192
  int o = i & 1023;
  double m = sums[o] / 8192.0;
  double var = sums[1024 + o] / 8192.0 - m * m;
  float inv = (float)(1.0 / sqrt(var + (double)EPSF));
  float y = keyf(mkeys[i]);
  float v = (y - (float)m) * inv * g[o] + bt[o];
  out[i] = (v >= 0.f) ? v : 0.2f * v;
}

// ============================ launch ====================================
static size_t ec_lds_bytes(int O, int CB, size_t accsz) {
  size_t stage = (size_t)CB * (O + 4) * 4 + (size_t)8 * CB * 24 * 4
               + (size_t)8 * KK * 4;
  size_t red = (size_t)16 * O * accsz;
  return stage > red ? stage : red;
}

extern "C" void kernel_launch(void* const* d_in, const int* in_sizes, int n_in,
                              void* d_out, int out_size, void* d_ws, size_t ws_size,
                              hipStream_t stream)
{
  (void)in_sizes; (void)n_in; (void)out_size; (void)ws_size;
  const float* x0 = (const float*)d_in[0];
  const float* W1 = (const float*)d_in[1];
  const float* g1 = (const float*)d_in[2];
  const float* b1 = (const float*)d_in[3];
  const float* W2 = (const float*)d_in[4];
  const float* g2 = (const float*)d_in[5];
  const float* b2 = (const float*)d_in[6];
  const float* W3 = (const float*)d_in[7];
  const float* g3 = (const float*)d_in[8];
  const float* b3 = (const float*)d_in[9];
  const float* W4 = (const float*)d_in[10];
  const float* g4 = (const float*)d_in[11];
  const float* b4 = (const float*)d_in[12];
  const float* W5 = (const float*)d_in[13];
  const float* g5 = (const float*)d_in[14];
  const float* b5 = (const float*)d_in[15];
  float* outp = (float*)d_out;

  char* w = (char*)d_ws;
  double*   sums   = (double*)w;   w += 5 * 2048 * sizeof(double);            // 80 KB
  unsigned* mkeys  = (unsigned*)w; w += (size_t)BB * 1024 * sizeof(unsigned); // 32 KB
  int*      idxbuf = (int*)w;      w += (size_t)BB * NPTS * KK * sizeof(int); // 640 KB
  char*     yraw   = w;            w += (size_t)BB * NPTS * 128 * sizeof(double); // 8 MB
  char*     ycbuf  = w;            w += (size_t)BB * NPTS * 128 * sizeof(double); // 8 MB
  float*    cat    = (float*)w;    // 16 MB

  double* sumsL[5] = {sums, sums + 2048, sums + 4096, sums + 6144, sums + 8192};

  const long catbs = 512L * NPTS;
  dim3 gknn(NPTS / 8, BB);
  dim3 gec(NPTS / 8, BB);

  hipMemsetAsync(sums, 0, 5 * 2048 * sizeof(double) + (size_t)BB * 1024 * sizeof(unsigned),
                 stream);

  // ---- layer 1: x0 (C=3) -> cat[0:64), fp64 acc ----
  knn2_kernel<3, 3><<<gknn, 256, 0, stream>>>(x0, 3L * NPTS, idxbuf);
  cacc_kernel<double, 3, 64, 3, 64><<<dim3(NPTS / 64, BB), 256, 0, stream>>>(
      x0, 3L * NPTS, W1, (double*)ycbuf);
  ec_fused<double, 3, 64, 1, 3><<<gec, 512, ec_lds_bytes(64, 3, 8), stream>>>(
      x0, 3L * NPTS, idxbuf, W1, (const double*)ycbuf, sumsL[0], (double*)yraw);
  ec_norm<double, 64, 6><<<BB * 64 * NPTS / 256, 256, 0, stream>>>(
      (const double*)yraw, sumsL[0], g1, b1, cat);

  // ---- layer 2: cat[0:64) -> cat[64:128), fp64 acc ----
  knn2_kernel<64, 8><<<gknn, 256, 0, stream>>>(cat, catbs, idxbuf);
  cacc_kernel<double, 64, 64, 16, 64><<<dim3(NPTS / 64, BB), 256, 0, stream>>>(
      cat, catbs, W2, (double*)ycbuf);
  ec_fused<double, 64, 64, 1, 16><<<gec, 512, ec_lds_bytes(64, 16, 8), stream>>>(
      cat, catbs, idxbuf, W2, (const double*)ycbuf, sumsL[1], (double*)yraw);
  ec_norm<double, 64, 6><<<BB * 64 * NPTS / 256, 256, 0, stream>>>(
      (const double*)yraw, sumsL[1], g2, b2, cat + 64 * NPTS);

  // ---- layer 3: cat[64:128) -> cat[128:256), fp64 acc ----
  knn2_kernel<64, 8><<<gknn, 256, 0, stream>>>(cat + 64 * NPTS, catbs, idxbuf);
  cacc_kernel<double, 64, 128, 16, 32><<<dim3(NPTS / 32, BB), 256, 0, stream>>>(
      cat + 64 * NPTS, catbs, W3, (double*)ycbuf);
  ec_fused<double, 64, 128, 2, 16><<<gec, 512, ec_lds_bytes(128, 16, 8), stream>>>(
      cat + 64 * NPTS, catbs, idxbuf, W3, (const double*)ycbuf, sumsL[2], (double*)yraw);
  ec_norm<double, 128, 7><<<BB * 128 * NPTS / 256, 256, 0, stream>>>(
      (const double*)yraw, sumsL[2], g3, b3, cat + 128 * NPTS);

  // ---- layer 4: cat[128:256) -> cat[256:512), fp32 acc (continuous path) ----
  knn2_kernel<128, 8><<<gknn, 256, 0, stream>>>(cat + 128 * NPTS, catbs, idxbuf);
  cacc_kernel<float, 128, 256, 16, 16><<<dim3(NPTS / 16, BB), 256, 0, stream>>>(
      cat + 128 * NPTS, catbs, W4, (float*)ycbuf);
  ec_fused<float, 128, 256, 4, 16><<<gec, 512, ec_lds_bytes(256, 16, 4), stream>>>(
      cat + 128 * NPTS, catbs, idxbuf, W4, (const float*)ycbuf, sumsL[3], (float*)yraw);
  ec_norm<float, 256, 8><<<BB * 256 * NPTS / 256, 256, 0, stream>>>(
      (const float*)yraw, sumsL[3], g4, b4, cat + 256 * NPTS);

  // ---- final 512->1024 conv + BN + lrelu + max over n ----
  dim3 gf(256, 2);
  fin_fused<<<gf, 256, 0, stream>>>(cat, W5, sumsL[4], mkeys);
  fin_norm<<<BB * 1024 / 256, 256, 0, stream>>>(mkeys, sumsL[4], g5, b5, outp);
}

// Round 8
// 1048.911 us; speedup vs baseline: 1.4810x; 1.4810x over previous
//
#include <hip/hip_runtime.h>
#include <math.h>

#define KK 20
#define NPTS 1024
#define BB 8
#define EPSF 1e-5f

// ====================== KNN v3: wave-per-point ==========================
// 512 thr = 8 waves = 16 points/block. xx accumulated per-thread from its
// own prefetch regs (thread t owns m=2t,2t+1), fp64 fma ascending c ->
// bitwise equal to the dot chain, so self distance is exactly 0.
// Selection: 20 rounds of local argmax over 16 regs + 64-lane butterfly
// (lowest-index tie-break), no __syncthreads.
__device__ __forceinline__ void select20(double (&d)[16], int lane, int* orow)
{
  int keep = 0;
  for (int s = 0; s < KK; ++s) {
    double bd = d[0]; int bj = 0;
    #pragma unroll
    for (int j = 1; j < 16; ++j)
      if (d[j] > bd) { bd = d[j]; bj = j; }     // strict > keeps lowest j (lowest m)
    int bi = bj * 64 + lane;
    #pragma unroll
    for (int o = 1; o < 64; o <<= 1) {
      double od = __shfl_xor(bd, o, 64);
      int    oi = __shfl_xor(bi, o, 64);
      if (od > bd || (od == bd && oi < bi)) { bd = od; bi = oi; }
    }
    if (lane == s) keep = bi;
    if ((bi & 63) == lane) {
      int jw = bi >> 6;
      #pragma unroll
      for (int j = 0; j < 16; ++j)
        if (j == jw) d[j] = -INFINITY;
    }
  }
  if (lane < KK) orow[lane] = keep;
}

template <int C, int CH>
__global__ __launch_bounds__(512, 4) void knn3_kernel(
    const float* __restrict__ x, long bstride,
    int* __restrict__ idx_out)
{
  const int t = threadIdx.x, w = t >> 6, lane = t & 63;
  const int b = blockIdx.y;
  const int n0 = blockIdx.x * 16;
  const int pa = n0 + 2 * w, pb = pa + 1;
  __shared__ float  xs[CH][NPTS];     // CH*4 KB
  __shared__ double xxs[NPTS];        // 8 KB
  const float* xb = x + (long)b * bstride;

  float2 r2[CH];
  #pragma unroll
  for (int j = 0; j < CH; ++j)
    r2[j] = *(const float2*)&xb[(long)j * NPTS + 2 * t];

  double xx0 = 0.0, xx1 = 0.0;        // m = 2t, 2t+1
  double dotA[16], dotB[16];
  #pragma unroll
  for (int j = 0; j < 16; ++j) { dotA[j] = 0.0; dotB[j] = 0.0; }

  for (int c0 = 0; c0 < C; c0 += CH) {
    __syncthreads();                  // prev compute done reading xs
    #pragma unroll
    for (int j = 0; j < CH; ++j)
      *(float2*)&xs[j][2 * t] = r2[j];
    #pragma unroll
    for (int j = 0; j < CH; ++j) {    // xx from own regs, ascending c
      double v0 = (double)r2[j].x; xx0 = fma(v0, v0, xx0);
      double v1 = (double)r2[j].y; xx1 = fma(v1, v1, xx1);
    }
    __syncthreads();
    if (c0 + CH < C) {                // prefetch next chunk (overlaps compute)
      #pragma unroll
      for (int j = 0; j < CH; ++j)
        r2[j] = *(const float2*)&xb[(long)(c0 + CH + j) * NPTS + 2 * t];
    }
    #pragma unroll
    for (int cc = 0; cc < CH; ++cc) {
      double ca = (double)xs[cc][pa]; // wave-uniform broadcast
      double cb = (double)xs[cc][pb];
      #pragma unroll
      for (int j = 0; j < 16; ++j) {
        double v = (double)xs[cc][j * 64 + lane];
        dotA[j] = fma(ca, v, dotA[j]);
        dotB[j] = fma(cb, v, dotB[j]);
      }
    }
  }
  xxs[2 * t]     = xx0;
  xxs[2 * t + 1] = xx1;
  __syncthreads();

  double xxA = xxs[pa], xxB = xxs[pb];
  double dA[16], dB[16];
  #pragma unroll
  for (int j = 0; j < 16; ++j) {
    double xm = xxs[j * 64 + lane];
    dA[j] = (2.0 * dotA[j] - xxA) - xm;   // m==pa: (2X-X)-X == 0 exactly
    dB[j] = (2.0 * dotB[j] - xxB) - xm;
  }
  select20(dA, lane, idx_out + ((long)b * NPTS + pa) * KK);
  select20(dB, lane, idx_out + ((long)b * NPTS + pb) * KK);
}

// =============== center-term GEMV: Yc[b][n][o] = sum_c wd*x ============
// wd = (W2-W1) in fp32, AccT accumulate, c ascending -> bit-identical to
// the original in-ec cacc chain.
template <typename AccT, int C, int O, int CB2, int TN>
__global__ __launch_bounds__(256) void cacc_kernel(
    const float* __restrict__ x, long bstride,
    const float* __restrict__ W,
    AccT* __restrict__ Yc)
{
  const int t = threadIdx.x, b = blockIdx.y;
  const int o = t & (O - 1);
  const int nbase = (t / O) * 16;
  const int nn0 = blockIdx.x * TN;
  __shared__ float s_wd[CB2 * O];
  __shared__ float s_xs[CB2 * TN];
  const float* xb = x + (long)b * bstride;

  AccT acc[16];
  #pragma unroll
  for (int j = 0; j < 16; ++j) acc[j] = (AccT)0;

  for (int c0 = 0; c0 < C; c0 += CB2) {
    __syncthreads();
    for (int i = t; i < CB2 * O; i += 256) {
      int oo = i / CB2, cc = i - oo * CB2;
      float a  = W[(long)oo * (2 * C) + c0 + cc];
      float b2 = W[(long)oo * (2 * C) + C + c0 + cc];
      s_wd[cc * O + oo] = b2 - a;
    }
    for (int i = t; i < CB2 * TN; i += 256) {
      int cc = i / TN, nn = i - cc * TN;
      s_xs[cc * TN + nn] = xb[(long)(c0 + cc) * NPTS + nn0 + nn];
    }
    __syncthreads();
    #pragma unroll
    for (int cc = 0; cc < CB2; ++cc) {
      float wv = s_wd[cc * O + o];
      #pragma unroll
      for (int j = 0; j < 16; ++j)
        acc[j] += (AccT)wv * (AccT)s_xs[cc * TN + nbase + j];
    }
  }
  #pragma unroll
  for (int j = 0; j < 16; ++j) {
    int n = nn0 + nbase + j;
    Yc[((long)b * NPTS + n) * O + o] = acc[j];
  }
}

// ==================== Fused EdgeConv (single pass) ======================
// y[o][n][k] = sum_c w1[o][c]*x[c][j_k] + Yc[o][n]   (center term hoisted)
// Raw max over k (norm+lrelu monotone, gamma>0) + sum/sumsq for BN stats.
// Block: 512 thr = 8 waves = 8 points; lane owns RO channels. w1-only LDS,
// xg k-contiguous -> per cc: 1 strided b128 + 5 broadcast b128 vs 80 FMA.
template <typename AccT, int C, int O, int RO, int CB>
__global__ __launch_bounds__(512, 4) void ec_fused(
    const float* __restrict__ x, long bstride,
    const int* __restrict__ idx,
    const float* __restrict__ W,
    const AccT* __restrict__ Yc,
    double* __restrict__ sums,
    AccT* __restrict__ yraw)          // [b][n][O] raw max over k
{
  const int t = threadIdx.x, b = blockIdx.y;
  const int p = t >> 6, lane = t & 63;
  const int n0 = blockIdx.x * 8;
  const int n = n0 + p;
  const int obase = lane * RO;
  const int OP = O + 4;
  const float* xb = x + (long)b * bstride;

  extern __shared__ char smraw[];
  float* s_w1 = (float*)smraw;               // [CB][OP]
  float* s_xg = s_w1 + CB * OP;              // [8][CB][24] gathered nbr x
  int*   s_jj = (int*)(s_xg + 8 * CB * 24);  // [8][KK]
  AccT*  red  = (AccT*)smraw;                // epilogue alias: [2][8][O]

  if (t < 8 * KK) {
    int pp = t / KK, k = t - pp * KK;
    s_jj[t] = idx[((long)b * NPTS + (n0 + pp)) * KK + k];
  }

  AccT kacc[RO][KK];
  #pragma unroll
  for (int r = 0; r < RO; ++r)
    #pragma unroll
    for (int k = 0; k < KK; ++k) kacc[r][k] = (AccT)0;

  for (int c0 = 0; c0 < C; c0 += CB) {
    __syncthreads();
    for (int i = t; i < CB * O; i += 512) {
      int o = i / CB, cc = i - o * CB;
      s_w1[cc * OP + o] = W[(long)o * (2 * C) + c0 + cc];
    }
    for (int i = t; i < 8 * CB * KK; i += 512) {
      int k = i % KK; int pc = i / KK;
      int cc = pc % CB; int pp = pc / CB;
      s_xg[(pp * CB + cc) * 24 + k] = xb[(long)(c0 + cc) * NPTS + s_jj[pp * KK + k]];
    }
    __syncthreads();
    for (int cc = 0; cc < CB; ++cc) {
      float wv[RO];
      if constexpr (RO == 4) {
        float4 a = *(const float4*)&s_w1[cc * OP + obase];
        wv[0]=a.x; wv[1]=a.y; wv[2]=a.z; wv[3]=a.w;
      } else if constexpr (RO == 2) {
        float2 a = *(const float2*)&s_w1[cc * OP + obase];
        wv[0]=a.x; wv[1]=a.y;
      } else {
        wv[0] = s_w1[cc * OP + obase];
      }
      const float* fp = s_xg + (p * CB + cc) * 24;
      #pragma unroll
      for (int k4 = 0; k4 < KK; k4 += 4) {
        float4 f4 = *(const float4*)(fp + k4);   // wave-uniform broadcast b128
        float fe[4] = {f4.x, f4.y, f4.z, f4.w};
        #pragma unroll
        for (int e = 0; e < 4; ++e) {
          #pragma unroll
          for (int r = 0; r < RO; ++r)
            kacc[r][k4 + e] += (AccT)wv[r] * (AccT)fe[e];
        }
      }
    }
  }

  AccT cacc[RO];
  const AccT* ycp = Yc + ((long)b * NPTS + n) * O + obase;
  #pragma unroll
  for (int r = 0; r < RO; ++r) cacc[r] = ycp[r];

  AccT psum[RO], psq[RO], pmx[RO];
  #pragma unroll
  for (int r = 0; r < RO; ++r) { psum[r] = (AccT)0; psq[r] = (AccT)0; pmx[r] = (AccT)(-INFINITY); }
  #pragma unroll
  for (int k = 0; k < KK; ++k) {
    #pragma unroll
    for (int r = 0; r < RO; ++r) {
      AccT y = kacc[r][k] + cacc[r];
      psum[r] += y; psq[r] += y * y;
      pmx[r] = (y > pmx[r]) ? y : pmx[r];
    }
  }
  #pragma unroll
  for (int r = 0; r < RO; ++r)
    yraw[((long)b * NPTS + n) * O + obase + r] = pmx[r];

  __syncthreads();
  #pragma unroll
  for (int r = 0; r < RO; ++r) {
    red[p * O + obase + r] = psum[r];
    red[8 * O + p * O + obase + r] = psq[r];
  }
  __syncthreads();
  if (t < O) {
    double s = 0.0, q = 0.0;
    #pragma unroll
    for (int w = 0; w < 8; ++w) {
      s += (double)red[w * O + t];
      q += (double)red[8 * O + w * O + t];
    }
    atomicAdd(&sums[t], s);
    atomicAdd(&sums[1024 + t], q);
  }
}

// normalize + lrelu the raw k-max, write into cat layout [b][o][n]
template <typename AccT, int O, int OL>
__global__ __launch_bounds__(256) void ec_norm(
    const AccT* __restrict__ yraw, const double* __restrict__ sums,
    const float* __restrict__ gamma, const float* __restrict__ beta,
    float* __restrict__ xout)
{
  int i = blockIdx.x * 256 + threadIdx.x;
  int n = i & (NPTS - 1);
  int o = (i >> 10) & (O - 1);
  int b = i >> (10 + OL);
  const double cnt = (double)BB * NPTS * KK;
  double m = sums[o] / cnt;
  double var = sums[1024 + o] / cnt - m * m;
  double inv = 1.0 / sqrt(var + (double)EPSF);
  AccT y = yraw[((long)b * NPTS + n) * O + o];
  AccT v = (y - (AccT)m) * (AccT)inv * (AccT)gamma[o] + (AccT)beta[o];
  v = (v >= (AccT)0) ? v : (AccT)0.2 * v;
  xout[(long)b * (512L * NPTS) + (long)o * NPTS + n] = (float)v;
}

// ============== Final 512->1024 conv, fused single pass =================
__device__ inline unsigned fkey(float f) {
  unsigned u = __float_as_uint(f);
  return (u & 0x80000000u) ? ~u : (u | 0x80000000u);
}
__device__ inline float keyf(unsigned k) {
  return __uint_as_float((k & 0x80000000u) ? (k ^ 0x80000000u) : ~k);
}

#define WST 524

__global__ __launch_bounds__(256) void fin_fused(
    const float* __restrict__ cat, const float* __restrict__ W5,
    double* __restrict__ sums, unsigned* __restrict__ mkeys)
{
  const int nt = blockIdx.x, ot = blockIdx.y, t = threadIdx.x;
  const int w = t >> 6, lane = t & 63;
  const int col0 = nt * 32;
  const int b = col0 >> 10;
  const int nb = col0 & 1023;

  __shared__ float sm[16 * WST + 16 * 32];
  float* s_w = sm;
  float* s_f = sm + 16 * WST;

  float acc[2][4][8];
  #pragma unroll
  for (int h = 0; h < 2; ++h)
    #pragma unroll
    for (int r = 0; r < 4; ++r)
      #pragma unroll
      for (int j = 0; j < 8; ++j) acc[h][r][j] = 0.f;

  for (int c0 = 0; c0 < 512; c0 += 16) {
    __syncthreads();
    for (int i = t; i < 16 * 512 / 4; i += 256) {
      int o = i >> 2, cq = (i & 3) * 4;
      float4 wv = *(const float4*)&W5[(long)(ot * 512 + o) * 512 + c0 + cq];
      s_w[(cq + 0) * WST + o] = wv.x;
      s_w[(cq + 1) * WST + o] = wv.y;
      s_w[(cq + 2) * WST + o] = wv.z;
      s_w[(cq + 3) * WST + o] = wv.w;
    }
    for (int i = t; i < 16 * 32; i += 256) {
      int cc = i >> 5, nn = i & 31;
      s_f[cc * 32 + nn] = cat[((long)b * 512 + c0 + cc) * 1024 + nb + nn];
    }
    __syncthreads();
    #pragma unroll
    for (int cc = 0; cc < 16; ++cc) {
      float4 wA = *(const float4*)&s_w[cc * WST + lane * 4];
      float4 wB = *(const float4*)&s_w[cc * WST + 256 + lane * 4];
      float4 f0 = *(const float4*)&s_f[cc * 32 + w * 8];
      float4 f1 = *(const float4*)&s_f[cc * 32 + w * 8 + 4];
      float wa[4] = {wA.x, wA.y, wA.z, wA.w};
      float wb[4] = {wB.x, wB.y, wB.z, wB.w};
      float fv[8] = {f0.x, f0.y, f0.z, f0.w, f1.x, f1.y, f1.z, f1.w};
      #pragma unroll
      for (int r = 0; r < 4; ++r)
        #pragma unroll
        for (int j = 0; j < 8; ++j) {
          acc[0][r][j] += wa[r] * fv[j];
          acc[1][r][j] += wb[r] * fv[j];
        }
    }
  }

  float psum[2][4], psq[2][4], pmx[2][4];
  #pragma unroll
  for (int h = 0; h < 2; ++h)
    #pragma unroll
    for (int r = 0; r < 4; ++r) {
      psum[h][r] = 0.f; psq[h][r] = 0.f; pmx[h][r] = -INFINITY;
      #pragma unroll
      for (int j = 0; j < 8; ++j) {
        float v = acc[h][r][j];
        psum[h][r] += v; psq[h][r] += v * v; pmx[h][r] = fmaxf(pmx[h][r], v);
      }
    }
  __syncthreads();
  float* red_s = sm;
  float* red_q = sm + 2048;
  float* red_m = sm + 4096;
  #pragma unroll
  for (int h = 0; h < 2; ++h)
    #pragma unroll
    for (int r = 0; r < 4; ++r) {
      int oo = h * 256 + lane * 4 + r;
      red_s[w * 512 + oo] = psum[h][r];
      red_q[w * 512 + oo] = psq[h][r];
      red_m[w * 512 + oo] = pmx[h][r];
    }
  __syncthreads();
  for (int oo = t; oo < 512; oo += 256) {
    float s = 0.f, q = 0.f, m = -INFINITY;
    #pragma unroll
    for (int ww = 0; ww < 4; ++ww) {
      s += red_s[ww * 512 + oo];
      q += red_q[ww * 512 + oo];
      m = fmaxf(m, red_m[ww * 512 + oo]);
    }
    int o = ot * 512 + oo;
    atomicAdd(&sums[o], (double)s);
    atomicAdd(&sums[1024 + o], (double)q);
    atomicMax(&mkeys[b * 1024 + o], fkey(m));
  }
}

__global__ __launch_bounds__(256) void fin_norm(
    const unsigned* __restrict__ mkeys, const double* __restrict__ sums,
    const float* __restrict__ g, const float* __restrict__ bt,
    float* __restrict__ out)
{
  int i = blockIdx.x * 256 + threadIdx.x;   // 8192
  int o = i & 1023;
  double m = sums[o] / 8192.0;
  double var = sums[1024 + o] / 8192.0 - m * m;
  float inv = (float)(1.0 / sqrt(var + (double)EPSF));
  float y = keyf(mkeys[i]);
  float v = (y - (float)m) * inv * g[o] + bt[o];
  out[i] = (v >= 0.f) ? v : 0.2f * v;
}

// ============================ launch ====================================
static size_t ec_lds_bytes(int O, int CB, size_t accsz) {
  size_t stage = (size_t)CB * (O + 4) * 4 + (size_t)8 * CB * 24 * 4
               + (size_t)8 * KK * 4;
  size_t red = (size_t)16 * O * accsz;
  return stage > red ? stage : red;
}

extern "C" void kernel_launch(void* const* d_in, const int* in_sizes, int n_in,
                              void* d_out, int out_size, void* d_ws, size_t ws_size,
                              hipStream_t stream)
{
  (void)in_sizes; (void)n_in; (void)out_size; (void)ws_size;
  const float* x0 = (const float*)d_in[0];
  const float* W1 = (const float*)d_in[1];
  const float* g1 = (const float*)d_in[2];
  const float* b1 = (const float*)d_in[3];
  const float* W2 = (const float*)d_in[4];
  const float* g2 = (const float*)d_in[5];
  const float* b2 = (const float*)d_in[6];
  const float* W3 = (const float*)d_in[7];
  const float* g3 = (const float*)d_in[8];
  const float* b3 = (const float*)d_in[9];
  const float* W4 = (const float*)d_in[10];
  const float* g4 = (const float*)d_in[11];
  const float* b4 = (const float*)d_in[12];
  const float* W5 = (const float*)d_in[13];
  const float* g5 = (const float*)d_in[14];
  const float* b5 = (const float*)d_in[15];
  float* outp = (float*)d_out;

  char* w = (char*)d_ws;
  double*   sums   = (double*)w;   w += 5 * 2048 * sizeof(double);            // 80 KB
  unsigned* mkeys  = (unsigned*)w; w += (size_t)BB * 1024 * sizeof(unsigned); // 32 KB
  int*      idxbuf = (int*)w;      w += (size_t)BB * NPTS * KK * sizeof(int); // 640 KB
  char*     yraw   = w;            w += (size_t)BB * NPTS * 128 * sizeof(double); // 8 MB
  char*     ycbuf  = w;            w += (size_t)BB * NPTS * 128 * sizeof(double); // 8 MB
  float*    cat    = (float*)w;    // 16 MB

  double* sumsL[5] = {sums, sums + 2048, sums + 4096, sums + 6144, sums + 8192};

  const long catbs = 512L * NPTS;
  dim3 gknn(NPTS / 16, BB);
  dim3 gec(NPTS / 8, BB);

  hipMemsetAsync(sums, 0, 5 * 2048 * sizeof(double) + (size_t)BB * 1024 * sizeof(unsigned),
                 stream);

  // ---- layer 1: x0 (C=3) -> cat[0:64), fp64 acc ----
  knn3_kernel<3, 3><<<gknn, 512, 0, stream>>>(x0, 3L * NPTS, idxbuf);
  cacc_kernel<double, 3, 64, 3, 64><<<dim3(NPTS / 64, BB), 256, 0, stream>>>(
      x0, 3L * NPTS, W1, (double*)ycbuf);
  ec_fused<double, 3, 64, 1, 3><<<gec, 512, ec_lds_bytes(64, 3, 8), stream>>>(
      x0, 3L * NPTS, idxbuf, W1, (const double*)ycbuf, sumsL[0], (double*)yraw);
  ec_norm<double, 64, 6><<<BB * 64 * NPTS / 256, 256, 0, stream>>>(
      (const double*)yraw, sumsL[0], g1, b1, cat);

  // ---- layer 2: cat[0:64) -> cat[64:128), fp64 acc ----
  knn3_kernel<64, 8><<<gknn, 512, 0, stream>>>(cat, catbs, idxbuf);
  cacc_kernel<double, 64, 64, 16, 64><<<dim3(NPTS / 64, BB), 256, 0, stream>>>(
      cat, catbs, W2, (double*)ycbuf);
  ec_fused<double, 64, 64, 1, 16><<<gec, 512, ec_lds_bytes(64, 16, 8), stream>>>(
      cat, catbs, idxbuf, W2, (const double*)ycbuf, sumsL[1], (double*)yraw);
  ec_norm<double, 64, 6><<<BB * 64 * NPTS / 256, 256, 0, stream>>>(
      (const double*)yraw, sumsL[1], g2, b2, cat + 64 * NPTS);

  // ---- layer 3: cat[64:128) -> cat[128:256), fp64 acc ----
  knn3_kernel<64, 8><<<gknn, 512, 0, stream>>>(cat + 64 * NPTS, catbs, idxbuf);
  cacc_kernel<double, 64, 128, 16, 32><<<dim3(NPTS / 32, BB), 256, 0, stream>>>(
      cat + 64 * NPTS, catbs, W3, (double*)ycbuf);
  ec_fused<double, 64, 128, 2, 16><<<gec, 512, ec_lds_bytes(128, 16, 8), stream>>>(
      cat + 64 * NPTS, catbs, idxbuf, W3, (const double*)ycbuf, sumsL[2], (double*)yraw);
  ec_norm<double, 128, 7><<<BB * 128 * NPTS / 256, 256, 0, stream>>>(
      (const double*)yraw, sumsL[2], g3, b3, cat + 128 * NPTS);

  // ---- layer 4: cat[128:256) -> cat[256:512), fp32 acc (continuous path) ----
  knn3_kernel<128, 8><<<gknn, 512, 0, stream>>>(cat + 128 * NPTS, catbs, idxbuf);
  cacc_kernel<float, 128, 256, 16, 16><<<dim3(NPTS / 16, BB), 256, 0, stream>>>(
      cat + 128 * NPTS, catbs, W4, (float*)ycbuf);
  ec_fused<float, 128, 256, 4, 16><<<gec, 512, ec_lds_bytes(256, 16, 4), stream>>>(
      cat + 128 * NPTS, catbs, idxbuf, W4, (const float*)ycbuf, sumsL[3], (float*)yraw);
  ec_norm<float, 256, 8><<<BB * 256 * NPTS / 256, 256, 0, stream>>>(
      (const float*)yraw, sumsL[3], g4, b4, cat + 256 * NPTS);

  // ---- final 512->1024 conv + BN + lrelu + max over n ----
  dim3 gf(256, 2);
  fin_fused<<<gf, 256, 0, stream>>>(cat, W5, sumsL[4], mkeys);
  fin_norm<<<BB * 1024 / 256, 256, 0, stream>>>(mkeys, sumsL[4], g5, b5, outp);
}